// Round 10
// baseline (435.121 us; speedup 1.0000x reference)
//
#include <hip/hip_runtime.h>
#include <hip/hip_fp16.h>

#define DFEAT 128
#define BNODES 256          // nodes per bucket (dst >> 8)
#define BSHIFT 8
#define B1CHUNK 4096        // edges per bin block (391 blocks)
#define SLABC 8192          // slab capacity per bucket (avg 4096, sigma ~64)
#define TPB_TILES 2         // staged GEMM tiles per block (R6 proven)
#define TPB1 2              // fused gemm1 tiles per block
#define TPBM 2              // mixed-dispatch (0-LDS) gemm tiles per block

typedef _Float16 f16x8 __attribute__((ext_vector_type(8)));
typedef _Float16 f16x4 __attribute__((ext_vector_type(4)));
typedef float f32x4 __attribute__((ext_vector_type(4)));

// Column permutation: col c stored at p(c) = (c&15)*8 + (c>>4); inverse c(p) = (p&7)*16 + (p>>3).
// Layer-1 dinv split: gemm1 writes RAW f16(x·W1); aggW applies dinv[c] per edge (L2-resident).
// Layers 2/3: dinv folded into gemm epilogue; agg is a plain sum.
// Schedule (10 dispatches):
//   memset gcnt; D1=[bin|packW]; D2=[bucketAB|gemm1]; D3=aggW-h1; D4=[aggW-h2|gemm2-h1(0-LDS)];
//   D5=gemm2-h2(staged); D6=agg2-h1; D7=[agg2-h2|gemm3-h1(0-LDS)]; D8=gemm3-h2; D9=aggF.
// Dependency audit: gemm_{l+1} rows [0,h) need only agg_l rows [0,h) (row-aligned);
// agg gathers need the WHOLE previous gemm (random cols) -> aggs start only after gemm-h2.
// Buffers: x->bufA(g1)->bufB(aggW)->bufC(g2)->bufA(agg2)->bufB(g3)->out(aggF); bufC aliases dead slab.

// ---- D1: fused {bin edges into per-bucket slabs} | {W pre-pack} ----
struct BinSh {
    int cnt[512];
    int off[512];
    int gbase[512];
    int sd[256];
    unsigned int buf[B1CHUNK];
    unsigned short bid[B1CHUNK];
};

__global__ __launch_bounds__(256) void binpack_k(const int* __restrict__ src, const int* __restrict__ dst,
                                                 int* __restrict__ gcnt, unsigned int* __restrict__ slab,
                                                 int E, int nbuck, int nbin,
                                                 const float* __restrict__ W0, const float* __restrict__ W1,
                                                 const float* __restrict__ W2,
                                                 const float* __restrict__ b0, const float* __restrict__ b1,
                                                 const float* __restrict__ b2,
                                                 _Float16* __restrict__ wpk, float* __restrict__ bp) {
    __shared__ __align__(16) BinSh B;
    int t = threadIdx.x;
    if (blockIdx.x >= nbin) {
        // ---- packW body (no LDS) ----
        int idx = (blockIdx.x - nbin) * 256 + t;    // 0 .. 49151
        if (idx < 49152) {
            int layer = idx >> 14;
            int e = idx & 16383;
            int k = e >> 7;
            int nn = e & 127;
            const float* W = (layer == 0) ? W0 : ((layer == 1) ? W1 : W2);
            int ksrc = (layer == 0) ? k : (((k & 7) << 4) | (k >> 3));
            float v = W[ksrc * DFEAT + nn];
            int kc = k >> 5, quad = (k >> 3) & 3, j = k & 7;
            int ct = nn >> 4;
            int pos = ((ct * 4 + kc) * 64 + quad * 16 + (nn & 15)) * 8 + j;
            wpk[(size_t)layer * 16384 + pos] = (_Float16)v;
            if (idx < 384) {
                int l = idx >> 7, p = idx & 127;
                int c = ((p & 7) << 4) | (p >> 3);
                const float* bb = (l == 0) ? b0 : ((l == 1) ? b1 : b2);
                bp[l * 128 + p] = bb[c];
            }
        }
        return;
    }
    // ---- bin body (R6-proven) ----
    int base = blockIdx.x * B1CHUNK;
    int nloc = E - base;
    if (nloc > B1CHUNK) nloc = B1CHUNK;
    B.cnt[t] = 0;
    B.cnt[t + 256] = 0;
    __syncthreads();
    int k = t;
    for (; k + 768 < nloc; k += 1024) {
        int d0 = dst[base + k], d1 = dst[base + k + 256], d2 = dst[base + k + 512], d3 = dst[base + k + 768];
        atomicAdd(&B.cnt[d0 >> BSHIFT], 1);
        atomicAdd(&B.cnt[d1 >> BSHIFT], 1);
        atomicAdd(&B.cnt[d2 >> BSHIFT], 1);
        atomicAdd(&B.cnt[d3 >> BSHIFT], 1);
    }
    for (; k < nloc; k += 256) atomicAdd(&B.cnt[dst[base + k] >> BSHIFT], 1);
    __syncthreads();
    int v0 = B.cnt[2 * t], v1 = B.cnt[2 * t + 1];
    int tsum = v0 + v1;
    B.sd[t] = tsum;
    __syncthreads();
    for (int o = 1; o < 256; o <<= 1) {
        int x = (t >= o) ? B.sd[t - o] : 0;
        __syncthreads();
        B.sd[t] += x;
        __syncthreads();
    }
    int texcl = B.sd[t] - tsum;
    B.off[2 * t] = texcl;
    B.off[2 * t + 1] = texcl + v0;
    if (2 * t < nbuck && v0 > 0) B.gbase[2 * t] = atomicAdd(&gcnt[2 * t], v0);
    if (2 * t + 1 < nbuck && v1 > 0) B.gbase[2 * t + 1] = atomicAdd(&gcnt[2 * t + 1], v1);
    __syncthreads();
    k = t;
    for (; k + 768 < nloc; k += 1024) {
        int d0 = dst[base + k], d1 = dst[base + k + 256], d2 = dst[base + k + 512], d3 = dst[base + k + 768];
        int s0 = src[base + k], s1 = src[base + k + 256], s2 = src[base + k + 512], s3 = src[base + k + 768];
        int b0_ = d0 >> BSHIFT, b1_ = d1 >> BSHIFT, b2_ = d2 >> BSHIFT, b3_ = d3 >> BSHIFT;
        int r0 = atomicAdd(&B.off[b0_], 1); B.buf[r0] = ((unsigned)s0 << BSHIFT) | (unsigned)(d0 & (BNODES - 1)); B.bid[r0] = (unsigned short)b0_;
        int r1 = atomicAdd(&B.off[b1_], 1); B.buf[r1] = ((unsigned)s1 << BSHIFT) | (unsigned)(d1 & (BNODES - 1)); B.bid[r1] = (unsigned short)b1_;
        int r2 = atomicAdd(&B.off[b2_], 1); B.buf[r2] = ((unsigned)s2 << BSHIFT) | (unsigned)(d2 & (BNODES - 1)); B.bid[r2] = (unsigned short)b2_;
        int r3 = atomicAdd(&B.off[b3_], 1); B.buf[r3] = ((unsigned)s3 << BSHIFT) | (unsigned)(d3 & (BNODES - 1)); B.bid[r3] = (unsigned short)b3_;
    }
    for (; k < nloc; k += 256) {
        int d = dst[base + k];
        int s = src[base + k];
        int b = d >> BSHIFT;
        int r = atomicAdd(&B.off[b], 1);
        B.buf[r] = ((unsigned)s << BSHIFT) | (unsigned)(d & (BNODES - 1));
        B.bid[r] = (unsigned short)b;
    }
    __syncthreads();
    k = t;
    for (; k + 768 < nloc; k += 1024) {
#pragma unroll
        for (int u = 0; u < 4; ++u) {
            int kk = k + u * 256;
            int b = B.bid[kk];
            int o0 = B.off[b] - B.cnt[b];
            int pos = B.gbase[b] + (kk - o0);
            if (pos < SLABC) slab[(size_t)b * SLABC + pos] = B.buf[kk];
        }
    }
    for (; k < nloc; k += 256) {
        int b = B.bid[k];
        int o0 = B.off[b] - B.cnt[b];
        int pos = B.gbase[b] + (k - o0);
        if (pos < SLABC) slab[(size_t)b * SLABC + pos] = B.buf[k];
    }
}

__device__ inline f16x8 ldA8(const float* p) {
    float4 a = *(const float4*)p;
    float4 b = *(const float4*)(p + 4);
    return f16x8{(_Float16)a.x, (_Float16)a.y, (_Float16)a.z, (_Float16)a.w,
                 (_Float16)b.x, (_Float16)b.y, (_Float16)b.z, (_Float16)b.w};
}
__device__ inline f16x8 ldA8(const __half* p) { return *(const f16x8*)p; }
__device__ inline f16x8 zero8() {
    return f16x8{(_Float16)0.f, (_Float16)0.f, (_Float16)0.f, (_Float16)0.f,
                 (_Float16)0.f, (_Float16)0.f, (_Float16)0.f, (_Float16)0.f};
}

// ---- D2: fused {bucketAB} | {layer-1 GEMM, W->LDS, direct-A, raw (no dinv)} ----
// bucketAB: 391 blocks at 1.5/CU was latency-bound and underutilized; gemm1's 782
// blocks fill the idle capacity. LDS overlay: bucketAB 35.25 KB | gemm1 wl 32 KB.
__global__ __launch_bounds__(256) void bktg1_k(const unsigned int* __restrict__ slab,
                                               const int* __restrict__ gcnt,
                                               int* __restrict__ rp, float* __restrict__ dinv,
                                               int* __restrict__ cols, int N, int nbuck,
                                               const float* __restrict__ A, const _Float16* __restrict__ wfrag,
                                               __half* __restrict__ C, int ntiles) {
    __shared__ __align__(16) char smem[36096];
    int t = threadIdx.x;
    if (blockIdx.x >= nbuck) {
        // ---- gemm1: C_perm = raw f16(A @ W1) ----
        _Float16* wl = (_Float16*)smem;
        const int wv_ = t >> 6;
        const int lane = t & 63;
        const int m = lane & 15;
        const int q = lane >> 4;
        for (int c = t; c < 2048; c += 256)
            *(f16x8*)&wl[c * 8] = *(const f16x8*)&wfrag[c * 8];
        __syncthreads();
        int t0 = (blockIdx.x - nbuck) * TPB1;
        int tend = t0 + TPB1;
        if (tend > ntiles) tend = ntiles;
        for (int tile = t0; tile < tend; ++tile) {
            int row0 = tile * 64;
            int ga = row0 + wv_ * 16 + m;
            f16x8 af[4];
            if (ga < N) {
#pragma unroll
                for (int kc = 0; kc < 4; ++kc)
                    af[kc] = ldA8(&A[(size_t)ga * DFEAT + kc * 32 + q * 8]);
            } else {
#pragma unroll
                for (int kc = 0; kc < 4; ++kc) af[kc] = zero8();
            }
            f32x4 acc[8];
#pragma unroll
            for (int ct = 0; ct < 8; ++ct) acc[ct] = (f32x4){0.f, 0.f, 0.f, 0.f};
#pragma unroll
            for (int ct = 0; ct < 8; ++ct) {
#pragma unroll
                for (int kc = 0; kc < 4; ++kc) {
                    f16x8 bf = *(f16x8*)&wl[((ct * 4 + kc) * 64 + lane) * 8];
                    acc[ct] = __builtin_amdgcn_mfma_f32_16x16x32_f16(af[kc], bf, acc[ct], 0, 0, 0);
                }
            }
            const int rbase = row0 + wv_ * 16 + q * 4;
#pragma unroll
            for (int r = 0; r < 4; ++r) {
                int gr = rbase + r;
                if (gr < N) {
                    f16x8 o;
#pragma unroll
                    for (int ct = 0; ct < 8; ++ct) o[ct] = (_Float16)acc[ct][r];
                    *(f16x8*)&C[(size_t)gr * DFEAT + m * 8] = o;
                }
            }
        }
        return;
    }
    // ---- bucketAB body (proven) ----
    int* cnt  = (int*)smem;
    int* cur  = (int*)(smem + 1024);
    int* psum = (int*)(smem + 2048);
    int* outb = (int*)(smem + 3072);   // 8192 ints = 32 KB
    int b = blockIdx.x;
    int n0 = b << BSHIFT;
    int nn = N - n0;
    if (nn > BNODES) nn = BNODES;
    int ne_raw = gcnt[b];
    int ne = ne_raw > SLABC ? SLABC : ne_raw;
    const unsigned int* sl = slab + (size_t)b * SLABC;
    int part = 0;
    for (int i = t; i < b; i += 256) part += gcnt[i];
    psum[t] = part;
    cnt[t] = 0;
    __syncthreads();
    for (int o = 128; o > 0; o >>= 1) {
        if (t < o) psum[t] += psum[t + o];
        __syncthreads();
    }
    int base = psum[0];
    int k = t;
    for (; k + 768 < ne; k += 1024) {
        unsigned a0 = sl[k], a1 = sl[k + 256], a2 = sl[k + 512], a3 = sl[k + 768];
        atomicAdd(&cnt[a0 & (BNODES - 1)], 1);
        atomicAdd(&cnt[a1 & (BNODES - 1)], 1);
        atomicAdd(&cnt[a2 & (BNODES - 1)], 1);
        atomicAdd(&cnt[a3 & (BNODES - 1)], 1);
    }
    for (; k < ne; k += 256) atomicAdd(&cnt[sl[k] & (BNODES - 1)], 1);
    __syncthreads();
    int deg = cnt[t];
    for (int o = 1; o < 256; o <<= 1) {
        int x = (t >= o) ? cnt[t - o] : 0;
        __syncthreads();
        cnt[t] += x;
        __syncthreads();
    }
    int excl = cnt[t] - deg;
    if (t < nn) {
        rp[n0 + t] = base + excl;
        dinv[n0 + t] = rsqrtf((float)(deg + 1));  // +1 self loop
    }
    if (b == nbuck - 1 && t == 0) rp[N] = base + ne_raw;
    cur[t] = excl;
    __syncthreads();
    k = t;
    for (; k + 768 < ne; k += 1024) {
        unsigned a0 = sl[k], a1 = sl[k + 256], a2 = sl[k + 512], a3 = sl[k + 768];
        int p0 = atomicAdd(&cur[a0 & (BNODES - 1)], 1); outb[p0] = (int)(a0 >> BSHIFT);
        int p1 = atomicAdd(&cur[a1 & (BNODES - 1)], 1); outb[p1] = (int)(a1 >> BSHIFT);
        int p2 = atomicAdd(&cur[a2 & (BNODES - 1)], 1); outb[p2] = (int)(a2 >> BSHIFT);
        int p3 = atomicAdd(&cur[a3 & (BNODES - 1)], 1); outb[p3] = (int)(a3 >> BSHIFT);
    }
    for (; k < ne; k += 256) {
        unsigned a = sl[k];
        int p = atomicAdd(&cur[a & (BNODES - 1)], 1);
        outb[p] = (int)(a >> BSHIFT);
    }
    __syncthreads();
    k = t;
    for (; k + 768 < ne; k += 1024) {
        int o0 = outb[k], o1 = outb[k + 256], o2 = outb[k + 512], o3 = outb[k + 768];
        cols[base + k] = o0;
        cols[base + k + 256] = o1;
        cols[base + k + 512] = o2;
        cols[base + k + 768] = o3;
    }
    for (; k < ne; k += 256) cols[base + k] = outb[k];
}

// ---------------- agg node bodies (wave-per-node, proven structure) ----------------

__device__ inline void aggW_node(const __half* __restrict__ T, const float* __restrict__ dinv,
                                 const int* __restrict__ rowptr, const int* __restrict__ cols,
                                 const float* __restrict__ biasp, __half* __restrict__ out,
                                 int wid, int lane) {
    int fb = lane * 2;
    float di = dinv[wid];
    float2 t0 = __half22float2(*(const __half2*)(T + (size_t)wid * DFEAT + fb));
    float ax = di * t0.x;
    float ay = di * t0.y;
    int s = rowptr[wid], e = rowptr[wid + 1];
    for (int p = s; p < e; ) {
        int take = e - p;
        if (take > 64) take = 64;
        int q = p + lane;
        if (q >= e) q = e - 1;
        int ci = cols[q];
        int j = 0;
        for (; j + 8 <= take; j += 8) {
            int c0 = __builtin_amdgcn_readlane(ci, j + 0);
            int c1 = __builtin_amdgcn_readlane(ci, j + 1);
            int c2 = __builtin_amdgcn_readlane(ci, j + 2);
            int c3 = __builtin_amdgcn_readlane(ci, j + 3);
            int c4 = __builtin_amdgcn_readlane(ci, j + 4);
            int c5 = __builtin_amdgcn_readlane(ci, j + 5);
            int c6 = __builtin_amdgcn_readlane(ci, j + 6);
            int c7 = __builtin_amdgcn_readlane(ci, j + 7);
            float w0 = dinv[c0], w1 = dinv[c1], w2 = dinv[c2], w3 = dinv[c3];
            float w4 = dinv[c4], w5 = dinv[c5], w6 = dinv[c6], w7 = dinv[c7];
            float2 v0 = __half22float2(*(const __half2*)(T + (size_t)c0 * DFEAT + fb));
            float2 v1 = __half22float2(*(const __half2*)(T + (size_t)c1 * DFEAT + fb));
            float2 v2 = __half22float2(*(const __half2*)(T + (size_t)c2 * DFEAT + fb));
            float2 v3 = __half22float2(*(const __half2*)(T + (size_t)c3 * DFEAT + fb));
            float2 v4 = __half22float2(*(const __half2*)(T + (size_t)c4 * DFEAT + fb));
            float2 v5 = __half22float2(*(const __half2*)(T + (size_t)c5 * DFEAT + fb));
            float2 v6 = __half22float2(*(const __half2*)(T + (size_t)c6 * DFEAT + fb));
            float2 v7 = __half22float2(*(const __half2*)(T + (size_t)c7 * DFEAT + fb));
            ax += w0 * v0.x; ay += w0 * v0.y;
            ax += w1 * v1.x; ay += w1 * v1.y;
            ax += w2 * v2.x; ay += w2 * v2.y;
            ax += w3 * v3.x; ay += w3 * v3.y;
            ax += w4 * v4.x; ay += w4 * v4.y;
            ax += w5 * v5.x; ay += w5 * v5.y;
            ax += w6 * v6.x; ay += w6 * v6.y;
            ax += w7 * v7.x; ay += w7 * v7.y;
        }
        for (; j < take; ++j) {
            int c = __builtin_amdgcn_readlane(ci, j);
            float w = dinv[c];
            float2 v = __half22float2(*(const __half2*)(T + (size_t)c * DFEAT + fb));
            ax += w * v.x; ay += w * v.y;
        }
        p += take;
    }
    float ox = fmaxf(di * ax + biasp[fb], 0.f);
    float oy = fmaxf(di * ay + biasp[fb + 1], 0.f);
    *(__half2*)(out + (size_t)wid * DFEAT + fb) = __floats2half2_rn(ox, oy);
}

__device__ inline float2 agg_row(const __half* __restrict__ T, const int* __restrict__ rowptr,
                                 const int* __restrict__ cols, int wid, int lane, int fb) {
    float2 t0 = __half22float2(*(const __half2*)(T + (size_t)wid * DFEAT + fb));
    float ax = t0.x;
    float ay = t0.y;
    int s = rowptr[wid], e = rowptr[wid + 1];
    for (int p = s; p < e; ) {
        int take = e - p;
        if (take > 64) take = 64;
        int q = p + lane;
        if (q >= e) q = e - 1;
        int ci = cols[q];
        int j = 0;
        for (; j + 8 <= take; j += 8) {
            int c0 = __builtin_amdgcn_readlane(ci, j + 0);
            int c1 = __builtin_amdgcn_readlane(ci, j + 1);
            int c2 = __builtin_amdgcn_readlane(ci, j + 2);
            int c3 = __builtin_amdgcn_readlane(ci, j + 3);
            int c4 = __builtin_amdgcn_readlane(ci, j + 4);
            int c5 = __builtin_amdgcn_readlane(ci, j + 5);
            int c6 = __builtin_amdgcn_readlane(ci, j + 6);
            int c7 = __builtin_amdgcn_readlane(ci, j + 7);
            float2 v0 = __half22float2(*(const __half2*)(T + (size_t)c0 * DFEAT + fb));
            float2 v1 = __half22float2(*(const __half2*)(T + (size_t)c1 * DFEAT + fb));
            float2 v2 = __half22float2(*(const __half2*)(T + (size_t)c2 * DFEAT + fb));
            float2 v3 = __half22float2(*(const __half2*)(T + (size_t)c3 * DFEAT + fb));
            float2 v4 = __half22float2(*(const __half2*)(T + (size_t)c4 * DFEAT + fb));
            float2 v5 = __half22float2(*(const __half2*)(T + (size_t)c5 * DFEAT + fb));
            float2 v6 = __half22float2(*(const __half2*)(T + (size_t)c6 * DFEAT + fb));
            float2 v7 = __half22float2(*(const __half2*)(T + (size_t)c7 * DFEAT + fb));
            ax += v0.x; ay += v0.y;
            ax += v1.x; ay += v1.y;
            ax += v2.x; ay += v2.y;
            ax += v3.x; ay += v3.y;
            ax += v4.x; ay += v4.y;
            ax += v5.x; ay += v5.y;
            ax += v6.x; ay += v6.y;
            ax += v7.x; ay += v7.y;
        }
        for (; j < take; ++j) {
            int c = __builtin_amdgcn_readlane(ci, j);
            float2 v = __half22float2(*(const __half2*)(T + (size_t)c * DFEAT + fb));
            ax += v.x; ay += v.y;
        }
        p += take;
    }
    return make_float2(ax, ay);
}

__device__ inline void agg_node(const __half* __restrict__ T, const float* __restrict__ dinv,
                                const int* __restrict__ rowptr, const int* __restrict__ cols,
                                const float* __restrict__ biasp, __half* __restrict__ out,
                                int wid, int lane) {
    int fb = lane * 2;
    float2 a = agg_row(T, rowptr, cols, wid, lane, fb);
    float dw = dinv[wid];
    float ox = fmaxf(dw * a.x + biasp[fb], 0.f);
    float oy = fmaxf(dw * a.y + biasp[fb + 1], 0.f);
    *(__half2*)(out + (size_t)wid * DFEAT + fb) = __floats2half2_rn(ox, oy);
}

// 0-LDS gemm tile (for mixed dispatches): direct-A, B-frags from L2-resident wpk,
// dinv folded. Zero static LDS so co-dispatched agg blocks keep full occupancy.
__device__ inline void gemm_tile_g(const __half* __restrict__ A, const _Float16* __restrict__ wfrag,
                                   const float* __restrict__ dinv, __half* __restrict__ C,
                                   int n, int tile) {
    const int tid = threadIdx.x;
    const int wv_ = tid >> 6;
    const int lane = tid & 63;
    const int m = lane & 15;
    const int q = lane >> 4;
    int row0 = tile * 64;
    int ga = row0 + wv_ * 16 + m;
    f16x8 af[4];
    if (ga < n) {
#pragma unroll
        for (int kc = 0; kc < 4; ++kc)
            af[kc] = *(const f16x8*)&A[(size_t)ga * DFEAT + kc * 32 + q * 8];
    } else {
#pragma unroll
        for (int kc = 0; kc < 4; ++kc) af[kc] = zero8();
    }
    f32x4 acc[8];
#pragma unroll
    for (int ct = 0; ct < 8; ++ct) acc[ct] = (f32x4){0.f, 0.f, 0.f, 0.f};
#pragma unroll
    for (int ct = 0; ct < 8; ++ct) {
#pragma unroll
        for (int kc = 0; kc < 4; ++kc) {
            f16x8 bf = *(const f16x8*)&wfrag[((size_t)(ct * 4 + kc) * 64 + lane) * 8];
            acc[ct] = __builtin_amdgcn_mfma_f32_16x16x32_f16(af[kc], bf, acc[ct], 0, 0, 0);
        }
    }
    const int rbase = row0 + wv_ * 16 + q * 4;
#pragma unroll
    for (int r = 0; r < 4; ++r) {
        int gr = rbase + r;
        if (gr < n) {
            float dr = dinv[gr];
            f16x8 o;
#pragma unroll
            for (int ct = 0; ct < 8; ++ct) o[ct] = (_Float16)(acc[ct][r] * dr);
            *(f16x8*)&C[(size_t)gr * DFEAT + m * 8] = o;
        }
    }
}

// ---- mixed dispatch: [agg rows [r0,r1) | gemm tiles [g0,g1) of the NEXT layer] ----
template <bool WEIGHTED>
__global__ __launch_bounds__(256) void aggGemm_k(const __half* __restrict__ T, const float* __restrict__ dinv,
                                                 const int* __restrict__ rowptr, const int* __restrict__ cols,
                                                 const float* __restrict__ biasp, __half* __restrict__ aggOut,
                                                 int r0, int r1, int nAggB,
                                                 const __half* __restrict__ Gsrc, const _Float16* __restrict__ wfrag,
                                                 __half* __restrict__ Gout, int g0, int g1, int n) {
    if ((int)blockIdx.x < nAggB) {
        int wid = r0 + (int)blockIdx.x * 4 + (threadIdx.x >> 6);
        if (wid >= r1) return;
        int lane = threadIdx.x & 63;
        if (WEIGHTED) aggW_node(T, dinv, rowptr, cols, biasp, aggOut, wid, lane);
        else          agg_node(T, dinv, rowptr, cols, biasp, aggOut, wid, lane);
    } else {
        int t0 = g0 + ((int)blockIdx.x - nAggB) * TPBM;
        for (int tt = 0; tt < TPBM; ++tt) {
            int tile = t0 + tt;
            if (tile >= g0 && tile < g1) gemm_tile_g(Gsrc, wfrag, dinv, Gout, n, tile);
        }
    }
}

// standalone range agg kernels
__global__ __launch_bounds__(256) void aggW_k(const __half* __restrict__ T, const float* __restrict__ dinv,
                                              const int* __restrict__ rowptr, const int* __restrict__ cols,
                                              const float* __restrict__ biasp, __half* __restrict__ out,
                                              int r0, int r1) {
    int wid = r0 + (int)blockIdx.x * 4 + (threadIdx.x >> 6);
    if (wid >= r1) return;
    aggW_node(T, dinv, rowptr, cols, biasp, out, wid, threadIdx.x & 63);
}

__global__ __launch_bounds__(256) void agg_k(const __half* __restrict__ T, const float* __restrict__ dinv,
                                             const int* __restrict__ rowptr, const int* __restrict__ cols,
                                             const float* __restrict__ biasp, __half* __restrict__ out,
                                             int r0, int r1) {
    int wid = r0 + (int)blockIdx.x * 4 + (threadIdx.x >> 6);
    if (wid >= r1) return;
    agg_node(T, dinv, rowptr, cols, biasp, out, wid, threadIdx.x & 63);
}

// final layer: no relu, f32 output, un-permutes at store (full range)
__global__ __launch_bounds__(256) void aggF_k(const __half* __restrict__ T, const float* __restrict__ dinv,
                                              const int* __restrict__ rowptr, const int* __restrict__ cols,
                                              const float* __restrict__ biasp,
                                              float* __restrict__ out, int n) {
    int wid = (int)((blockIdx.x * (size_t)blockDim.x + threadIdx.x) >> 6);
    int lane = threadIdx.x & 63;
    if (wid >= n) return;
    int fb = lane * 2;
    float2 a = agg_row(T, rowptr, cols, wid, lane, fb);
    float dw = dinv[wid];
    float ox = dw * a.x + biasp[fb];
    float oy = dw * a.y + biasp[fb + 1];
    int c0 = ((fb & 7) << 4) | (fb >> 3);
    int c1 = (((fb + 1) & 7) << 4) | ((fb + 1) >> 3);
    out[(size_t)wid * DFEAT + c0] = ox;
    out[(size_t)wid * DFEAT + c1] = oy;
}

// ---------------- standalone staged GEMM (h2 halves): R6-proven, tile-offset ----------------
__global__ __launch_bounds__(256) void gemmP_k(const __half* __restrict__ A, const _Float16* __restrict__ wfrag,
                                               const float* __restrict__ dinv, __half* __restrict__ C,
                                               int n, int tile0, int ntiles) {
    __shared__ _Float16 al[8192];     // A frags, swizzled (16 KB)
    __shared__ _Float16 wl[16384];    // W frags, linear copy (32 KB)
    const int tid = threadIdx.x;
    const int wv_ = tid >> 6;
    const int lane = tid & 63;
    const int t0 = tile0 + blockIdx.x * TPB_TILES;
    const int chunk = tid & 15;
    const int rsub = tid >> 4;
    const int kcS = chunk >> 2, quadS = chunk & 3;
    const int swzS = (kcS << 1) ^ (quadS & 1);

    for (int c = tid; c < 2048; c += 256)
        *(f16x8*)&wl[c * 8] = *(const f16x8*)&wfrag[c * 8];

    f16x8 pre[4];
    {
        int row0 = t0 * 64;
#pragma unroll
        for (int p = 0; p < 4; ++p) {
            int gr = row0 + p * 16 + rsub;
            pre[p] = (gr < n) ? ldA8(&A[(size_t)gr * DFEAT + chunk * 8]) : zero8();
        }
    }
    for (int tt = 0; tt < TPB_TILES; ++tt) {
        int tile = t0 + tt;
        if (tile >= ntiles) break;
        int row0 = tile * 64;
#pragma unroll
        for (int p = 0; p < 4; ++p) {
            int idx = (p * 4 + kcS) * 64 + quadS * 16 + rsub;
            *(f16x8*)&al[(idx ^ swzS) * 8] = pre[p];
        }
        __syncthreads();
        if (tt + 1 < TPB_TILES && tile + 1 < ntiles) {
            int nrow0 = (tile + 1) * 64;
#pragma unroll
            for (int p = 0; p < 4; ++p) {
                int gr = nrow0 + p * 16 + rsub;
                pre[p] = (gr < n) ? ldA8(&A[(size_t)gr * DFEAT + chunk * 8]) : zero8();
            }
        }
        f16x8 af[4];
        const int swzR = (lane >> 4) & 1;
#pragma unroll
        for (int kc = 0; kc < 4; ++kc) {
            int idx = (wv_ * 4 + kc) * 64 + lane;
            af[kc] = *(f16x8*)&al[(idx ^ (kc << 1) ^ swzR) * 8];
        }
        const int quad = lane >> 4, cb = lane & 15;
        const int rbase = row0 + wv_ * 16 + quad * 4;
        float ds[4];
#pragma unroll
        for (int r = 0; r < 4; ++r) ds[r] = (rbase + r < n) ? dinv[rbase + r] : 0.f;
        f32x4 acc[8];
#pragma unroll
        for (int ct = 0; ct < 8; ++ct) acc[ct] = (f32x4){0.f, 0.f, 0.f, 0.f};
#pragma unroll
        for (int ct = 0; ct < 8; ++ct) {
#pragma unroll
            for (int kc = 0; kc < 4; ++kc) {
                f16x8 bf = *(f16x8*)&wl[((ct * 4 + kc) * 64 + lane) * 8];
                acc[ct] = __builtin_amdgcn_mfma_f32_16x16x32_f16(af[kc], bf, acc[ct], 0, 0, 0);
            }
        }
#pragma unroll
        for (int r = 0; r < 4; ++r) {
            int gr = rbase + r;
            if (gr < n) {
                f16x8 o;
#pragma unroll
                for (int ct = 0; ct < 8; ++ct) o[ct] = (_Float16)(acc[ct][r] * ds[r]);
                *(f16x8*)&C[(size_t)gr * DFEAT + cb * 8] = o;
            }
        }
        __syncthreads();
    }
}

// ---------------- launch ----------------

extern "C" void kernel_launch(void* const* d_in, const int* in_sizes, int n_in,
                              void* d_out, int out_size, void* d_ws, size_t ws_size,
                              hipStream_t stream) {
    const float* x  = (const float*)d_in[0];
    const int*   ei = (const int*)d_in[1];
    const float* W1 = (const float*)d_in[2];
    const float* b1 = (const float*)d_in[3];
    const float* W2 = (const float*)d_in[4];
    const float* b2 = (const float*)d_in[5];
    const float* W3 = (const float*)d_in[6];
    const float* b3 = (const float*)d_in[7];
    float* out = (float*)d_out;

    const int N = in_sizes[0] / DFEAT;
    const int E = in_sizes[1] / 2;
    const int* srcp = ei;
    const int* dstp = ei + E;

    size_t off = 0;
    auto alloc = [&](size_t bytes) -> void* {
        void* p = (char*)d_ws + off;
        off += (bytes + 255) & ~(size_t)255;
        return p;
    };
    const int nbuck = (N + BNODES - 1) / BNODES;       // 391 for N=100000 (<=512)

    int*    gcnt = (int*)alloc(2048);
    int*    rp   = (int*)alloc((size_t)(N + 1) * 4);
    float*  dinv = (float*)alloc((size_t)N * 4);
    _Float16* wpk = (_Float16*)alloc((size_t)3 * 16384 * 2);   // pre-packed W frags
    float*  bp   = (float*)alloc(3 * 128 * 4);                 // permuted biases
    int*    cols = (int*)alloc((size_t)E * 4);
    __half* bufA = (__half*)alloc((size_t)N * DFEAT * 2);
    __half* bufB = (__half*)alloc((size_t)N * DFEAT * 2);
    // slab and bufC share one region: slab live D1-D2 only; bufC live D4-D7 only.
    size_t shBytes = (size_t)nbuck * SLABC * 4;                // 12.8 MB
    size_t cBytes  = (size_t)N * DFEAT * 2;                    // 25.6 MB
    void* shared = alloc(shBytes > cBytes ? shBytes : cBytes);
    unsigned int* slab = (unsigned int*)shared;
    __half* bufC = (__half*)shared;

    const int nbin = (E + B1CHUNK - 1) / B1CHUNK;
    int ntiles = (N + 63) / 64;
    int htiles = ntiles / 2;
    int hrows  = htiles * 64;
    int g1b    = (ntiles + TPB1 - 1) / TPB1;
    int gmixB  = (htiles + TPBM - 1) / TPBM;
    int gPB    = (ntiles - htiles + TPB_TILES - 1) / TPB_TILES;
    int aggB1  = (hrows + 3) / 4;
    int aggB2  = (N - hrows + 3) / 4;
    int aggFull = (int)(((size_t)N * 64 + 255) / 256);

    hipMemsetAsync(gcnt, 0, 2048, stream);
    // D1: [bin | packW]
    binpack_k<<<nbin + 192, 256, 0, stream>>>(srcp, dstp, gcnt, slab, E, nbuck, nbin,
                                              W1, W2, W3, b1, b2, b3, wpk, bp);
    // D2: [bucketAB | gemm1(raw, x -> bufA)]
    bktg1_k<<<nbuck + g1b, 256, 0, stream>>>(slab, gcnt, rp, dinv, cols, N, nbuck,
                                             x, wpk, bufA, ntiles);
    // D3: aggW rows [0, hrows)            bufA -> bufB
    aggW_k<<<aggB1, 256, 0, stream>>>(bufA, dinv, rp, cols, bp, bufB, 0, hrows);
    // D4: [aggW rows [hrows,N) | gemm2 tiles [0,htiles)]   bufB -> bufC
    aggGemm_k<true><<<aggB2 + gmixB, 256, 0, stream>>>(bufA, dinv, rp, cols, bp, bufB,
                                                       hrows, N, aggB2,
                                                       bufB, wpk + 16384, bufC, 0, htiles, N);
    // D5: gemm2 tiles [htiles, ntiles)    bufB -> bufC
    gemmP_k<<<gPB, 256, 0, stream>>>(bufB, wpk + 16384, dinv, bufC, N, htiles, ntiles);
    // D6: agg2 rows [0, hrows)            bufC -> bufA
    agg_k<<<aggB1, 256, 0, stream>>>(bufC, dinv, rp, cols, bp + 128, bufA, 0, hrows);
    // D7: [agg2 rows [hrows,N) | gemm3 tiles [0,htiles)]   bufA -> bufB
    aggGemm_k<false><<<aggB2 + gmixB, 256, 0, stream>>>(bufC, dinv, rp, cols, bp + 128, bufA,
                                                        hrows, N, aggB2,
                                                        bufA, wpk + 32768, bufB, 0, htiles, N);
    // D8: gemm3 tiles [htiles, ntiles)    bufA -> bufB
    gemmP_k<<<gPB, 256, 0, stream>>>(bufA, wpk + 32768, dinv, bufB, N, htiles, ntiles);
    // D9: final agg, full range           bufB -> out
    aggF_k<<<aggFull, 256, 0, stream>>>(bufB, dinv, rp, cols, bp + 256, out, N);
}